// Round 2
// baseline (203.692 us; speedup 1.0000x reference)
//
#include <hip/hip_runtime.h>
#include <math.h>

#define NB 8192
#define NI 12288
#define H0 256
#define H1 32
#define H2 32
#define MAXA 256
#define OUT_SCALE 300.0f
#define WDL_SCALE 200.0f

// ---------------------------------------------------------------------------
// Kernel 1: tiled transpose ft_w [H0][NI] -> ftT [NI][H0] (coalesced both ways)
// ---------------------------------------------------------------------------
__global__ __launch_bounds__(256) void nnue_ft_transpose(
    const float* __restrict__ src, float* __restrict__ dst)
{
    __shared__ float tile[64][65];           // +1 pad: no bank conflicts
    const int bx = blockIdx.x;               // NI/64 = 192 tiles
    const int by = blockIdx.y;               // H0/64 = 4 tiles
    const int tx = threadIdx.x;              // 64
    const int ty = threadIdx.y;              // 4
    const int col = bx * 64 + tx;
    for (int j = ty; j < 64; j += 4)
        tile[j][tx] = src[(size_t)(by * 64 + j) * NI + col];
    __syncthreads();
    const int h = by * 64 + tx;
    for (int j = ty; j < 64; j += 4)
        dst[(size_t)(bx * 64 + j) * H0 + h] = tile[tx][j];
}

// ---------------------------------------------------------------------------
// Kernel 2: one 256-thread block per batch row.
//   scan features (float4) -> nonzero index lists in LDS -> gather-accumulate
//   ft columns -> side-swapped concat -> 512->32->32->1 MLP -> sigmoid
// ---------------------------------------------------------------------------
__global__ __launch_bounds__(256) void nnue_fwd(
    const float* __restrict__ wf, const float* __restrict__ bf,
    const int* __restrict__ side,
    const float* __restrict__ ft,        // ftT [NI][H0] if tflag, else ft_w [H0][NI]
    const float* __restrict__ ft_b,
    const float* __restrict__ l1_w, const float* __restrict__ l1_b,
    const float* __restrict__ l2_w, const float* __restrict__ l2_b,
    const float* __restrict__ l3_w, const float* __restrict__ l3_b,
    float* __restrict__ out, int tflag)
{
    __shared__ int   idxW[MAXA], idxB[MAXA];
    __shared__ int   cnts[2];
    __shared__ float o0[2 * H0];
    __shared__ float o1[H1];

    const int row = blockIdx.x;
    const int t   = threadIdx.x;
    if (t < 2) cnts[t] = 0;
    __syncthreads();

    // ---- scan both feature rows, collect nonzero indices ----
    const float4* wf4 = (const float4*)(wf + (size_t)row * NI);
    const float4* bf4 = (const float4*)(bf + (size_t)row * NI);
    #pragma unroll
    for (int k = 0; k < NI / 4 / 256; ++k) {     // 12 iterations
        const int e = t + k * 256;
        const float4 v = wf4[e];
        const float4 u = bf4[e];
        const int base = e * 4;
        if (v.x != 0.f) idxW[atomicAdd(&cnts[0], 1)] = base;
        if (v.y != 0.f) idxW[atomicAdd(&cnts[0], 1)] = base + 1;
        if (v.z != 0.f) idxW[atomicAdd(&cnts[0], 1)] = base + 2;
        if (v.w != 0.f) idxW[atomicAdd(&cnts[0], 1)] = base + 3;
        if (u.x != 0.f) idxB[atomicAdd(&cnts[1], 1)] = base;
        if (u.y != 0.f) idxB[atomicAdd(&cnts[1], 1)] = base + 1;
        if (u.z != 0.f) idxB[atomicAdd(&cnts[1], 1)] = base + 2;
        if (u.w != 0.f) idxB[atomicAdd(&cnts[1], 1)] = base + 3;
    }
    __syncthreads();

    // ---- feature transform: thread t owns hidden unit h = t ----
    const int nW = cnts[0], nB = cnts[1];
    float accW = ft_b[t], accB = ft_b[t];
    if (tflag) {                                 // transposed: coalesced 1KB rows
        for (int i = 0; i < nW; ++i) accW += ft[(size_t)idxW[i] * H0 + t];
        for (int i = 0; i < nB; ++i) accB += ft[(size_t)idxB[i] * H0 + t];
    } else {                                     // fallback: strided (L3-served)
        const float* ftr = ft + (size_t)t * NI;
        for (int i = 0; i < nW; ++i) accW += ftr[idxW[i]];
        for (int i = 0; i < nB; ++i) accB += ftr[idxB[i]];
    }

    const bool s = side[row] != 0;
    const float wv = fminf(fmaxf(accW, 0.f), 1.f);
    const float bv = fminf(fmaxf(accB, 0.f), 1.f);
    o0[t]      = s ? wv : bv;
    o0[t + H0] = s ? bv : wv;
    __syncthreads();

    // ---- l1: 32 outputs x 512 inputs, 8 threads per output ----
    {
        const int j = t >> 3, p = t & 7;
        const float* wrow = l1_w + j * (2 * H0);
        float sum = 0.f;
        #pragma unroll
        for (int m = 0; m < 64; ++m) {
            const int k = p + 8 * m;             // stride-8: conflict-free LDS
            sum += wrow[k] * o0[k];
        }
        sum += __shfl_xor(sum, 1);
        sum += __shfl_xor(sum, 2);
        sum += __shfl_xor(sum, 4);
        if (p == 0) o1[j] = fminf(fmaxf(sum + l1_b[j], 0.f), 1.f);
    }
    __syncthreads();

    // ---- l2 (32x32) + l3 (1x32) + sigmoid, lanes 0..31 of wave 0 ----
    if (t < 32) {
        const float* wrow = l2_w + t * H1;
        float sum2 = 0.f;
        #pragma unroll
        for (int k = 0; k < H1; ++k) sum2 += wrow[k] * o1[k];
        const float o2v = fminf(fmaxf(sum2 + l2_b[t], 0.f), 1.f);
        float part = o2v * l3_w[t];
        part += __shfl_xor(part, 1);
        part += __shfl_xor(part, 2);
        part += __shfl_xor(part, 4);
        part += __shfl_xor(part, 8);
        part += __shfl_xor(part, 16);
        if (t == 0) {
            const float o3 = (part + l3_b[0]) * OUT_SCALE;
            out[row] = 1.f / (1.f + __expf(-o3 / WDL_SCALE));
        }
    }
}

extern "C" void kernel_launch(void* const* d_in, const int* in_sizes, int n_in,
                              void* d_out, int out_size, void* d_ws, size_t ws_size,
                              hipStream_t stream) {
    const float* wf   = (const float*)d_in[0];
    const float* bf   = (const float*)d_in[1];
    const int*   side = (const int*)d_in[2];     // bool -> int32 per harness convention
    const float* ft_w = (const float*)d_in[3];
    const float* ft_b = (const float*)d_in[4];
    const float* l1_w = (const float*)d_in[5];
    const float* l1_b = (const float*)d_in[6];
    const float* l2_w = (const float*)d_in[7];
    const float* l2_b = (const float*)d_in[8];
    const float* l3_w = (const float*)d_in[9];
    const float* l3_b = (const float*)d_in[10];
    float*       out  = (float*)d_out;

    const size_t needT = (size_t)NI * H0 * sizeof(float);   // 12.6 MB
    const int tflag = (ws_size >= needT) ? 1 : 0;
    const float* ft = ft_w;
    if (tflag) {
        float* ftT = (float*)d_ws;
        nnue_ft_transpose<<<dim3(NI / 64, H0 / 64), dim3(64, 4), 0, stream>>>(ft_w, ftT);
        ft = ftT;
    }
    nnue_fwd<<<NB, 256, 0, stream>>>(wf, bf, side, ft, ft_b,
                                     l1_w, l1_b, l2_w, l2_b, l3_w, l3_b,
                                     out, tflag);
}

// Round 4
// 183.435 us; speedup vs baseline: 1.1104x; 1.1104x over previous
//
#include <hip/hip_runtime.h>
#include <math.h>

#define NB 8192
#define NI 12288
#define H0 256
#define H1 32
#define H2 32
#define MAXA 256
#define OUT_SCALE 300.0f
#define WDL_SCALE 200.0f

typedef float f32x4 __attribute__((ext_vector_type(4)));   // clang vector: OK for nontemporal builtins

// ---------------------------------------------------------------------------
// Kernel 1: tiled transpose ft_w [H0][NI] -> ftT [NI][H0]
// ---------------------------------------------------------------------------
__global__ __launch_bounds__(256) void nnue_ft_transpose(
    const float* __restrict__ src, float* __restrict__ dst)
{
    __shared__ float tile[64][65];
    const int bx = blockIdx.x;               // NI/64 tiles
    const int by = blockIdx.y;               // H0/64 tiles
    const int tx = threadIdx.x;              // 64
    const int ty = threadIdx.y;              // 4
    const int col = bx * 64 + tx;
    for (int j = ty; j < 64; j += 4)
        tile[j][tx] = src[(size_t)(by * 64 + j) * NI + col];
    __syncthreads();
    const int h = by * 64 + tx;
    for (int j = ty; j < 64; j += 4)
        dst[(size_t)(bx * 64 + j) * H0 + h] = tile[tx][j];
}

// ---------------------------------------------------------------------------
// Kernel 2: one 256-thread block per batch row.
//   register-prefetched nontemporal scan -> index lists -> unrolled gather
//   -> side-swapped concat -> 512->32->32->1 MLP -> sigmoid
// ---------------------------------------------------------------------------
__global__ __launch_bounds__(256) void nnue_fwd(
    const float* __restrict__ wf, const float* __restrict__ bf,
    const int* __restrict__ side,
    const float* __restrict__ ft,        // ftT [NI][H0] if tflag, else ft_w [H0][NI]
    const float* __restrict__ ft_b,
    const float* __restrict__ l1_w, const float* __restrict__ l1_b,
    const float* __restrict__ l2_w, const float* __restrict__ l2_b,
    const float* __restrict__ l3_w, const float* __restrict__ l3_b,
    float* __restrict__ out, int tflag)
{
    __shared__ int   idxW[MAXA], idxB[MAXA];
    __shared__ int   cnts[2];
    __shared__ float o0[2 * H0];
    __shared__ float o1[H1];

    const int row = blockIdx.x;
    const int t   = threadIdx.x;
    if (t < 2) cnts[t] = 0;
    __syncthreads();

    const f32x4* wf4 = (const f32x4*)(wf + (size_t)row * NI);
    const f32x4* bf4 = (const f32x4*)(bf + (size_t)row * NI);
    const float ftb = ft_b[t];               // hoist bias load

    // ---- white: prefetch 12 float4 into regs (independent loads), then scan
    {
        f32x4 v[12];
        #pragma unroll
        for (int k = 0; k < 12; ++k)
            v[k] = __builtin_nontemporal_load(&wf4[t + k * 256]);
        #pragma unroll
        for (int k = 0; k < 12; ++k) {
            const int base = (t + k * 256) * 4;
            int m = (v[k].x != 0.f ? 1 : 0) | (v[k].y != 0.f ? 2 : 0)
                  | (v[k].z != 0.f ? 4 : 0) | (v[k].w != 0.f ? 8 : 0);
            while (m) {
                const int b = __ffs(m) - 1;
                m &= m - 1;
                idxW[atomicAdd(&cnts[0], 1)] = base + b;
            }
        }
    }
    // ---- black: same
    {
        f32x4 v[12];
        #pragma unroll
        for (int k = 0; k < 12; ++k)
            v[k] = __builtin_nontemporal_load(&bf4[t + k * 256]);
        #pragma unroll
        for (int k = 0; k < 12; ++k) {
            const int base = (t + k * 256) * 4;
            int m = (v[k].x != 0.f ? 1 : 0) | (v[k].y != 0.f ? 2 : 0)
                  | (v[k].z != 0.f ? 4 : 0) | (v[k].w != 0.f ? 8 : 0);
            while (m) {
                const int b = __ffs(m) - 1;
                m &= m - 1;
                idxB[atomicAdd(&cnts[1], 1)] = base + b;
            }
        }
    }
    __syncthreads();

    // ---- feature transform: thread t owns hidden unit h = t ----
    const int nW = cnts[0], nB = cnts[1];
    float accW, accB;
    if (tflag) {                             // coalesced 1KB rows, L2/L3-resident
        float a0 = 0.f, a1 = 0.f, a2 = 0.f, a3 = 0.f;
        int i = 0;
        for (; i + 4 <= nW; i += 4) {        // 4 independent loads in flight
            const int i0 = __builtin_amdgcn_readfirstlane(idxW[i]);
            const int i1 = __builtin_amdgcn_readfirstlane(idxW[i + 1]);
            const int i2 = __builtin_amdgcn_readfirstlane(idxW[i + 2]);
            const int i3 = __builtin_amdgcn_readfirstlane(idxW[i + 3]);
            a0 += ft[(size_t)i0 * H0 + t];
            a1 += ft[(size_t)i1 * H0 + t];
            a2 += ft[(size_t)i2 * H0 + t];
            a3 += ft[(size_t)i3 * H0 + t];
        }
        for (; i < nW; ++i)
            a0 += ft[(size_t)__builtin_amdgcn_readfirstlane(idxW[i]) * H0 + t];
        accW = ftb + ((a0 + a1) + (a2 + a3));

        float b0 = 0.f, b1 = 0.f, b2 = 0.f, b3 = 0.f;
        i = 0;
        for (; i + 4 <= nB; i += 4) {
            const int i0 = __builtin_amdgcn_readfirstlane(idxB[i]);
            const int i1 = __builtin_amdgcn_readfirstlane(idxB[i + 1]);
            const int i2 = __builtin_amdgcn_readfirstlane(idxB[i + 2]);
            const int i3 = __builtin_amdgcn_readfirstlane(idxB[i + 3]);
            b0 += ft[(size_t)i0 * H0 + t];
            b1 += ft[(size_t)i1 * H0 + t];
            b2 += ft[(size_t)i2 * H0 + t];
            b3 += ft[(size_t)i3 * H0 + t];
        }
        for (; i < nB; ++i)
            b0 += ft[(size_t)__builtin_amdgcn_readfirstlane(idxB[i]) * H0 + t];
        accB = ftb + ((b0 + b1) + (b2 + b3));
    } else {                                 // fallback: strided (cached)
        accW = ftb; accB = ftb;
        const float* ftr = ft + (size_t)t * NI;
        for (int i = 0; i < nW; ++i) accW += ftr[idxW[i]];
        for (int i = 0; i < nB; ++i) accB += ftr[idxB[i]];
    }

    const bool s = side[row] != 0;
    const float wv = fminf(fmaxf(accW, 0.f), 1.f);
    const float bv = fminf(fmaxf(accB, 0.f), 1.f);
    o0[t]      = s ? wv : bv;
    o0[t + H0] = s ? bv : wv;
    __syncthreads();

    // ---- l1: 32 outputs x 512 inputs, 8 threads per output ----
    {
        const int j = t >> 3, p = t & 7;
        const float* wrow = l1_w + j * (2 * H0);
        float sum = 0.f;
        #pragma unroll
        for (int m = 0; m < 64; ++m) {
            const int k = p + 8 * m;         // stride-8: conflict-free LDS
            sum += wrow[k] * o0[k];
        }
        sum += __shfl_xor(sum, 1);
        sum += __shfl_xor(sum, 2);
        sum += __shfl_xor(sum, 4);
        if (p == 0) o1[j] = fminf(fmaxf(sum + l1_b[j], 0.f), 1.f);
    }
    __syncthreads();

    // ---- l2 (32x32) + l3 (1x32) + sigmoid ----
    if (t < 32) {
        const float* wrow = l2_w + t * H1;
        float sum2 = 0.f;
        #pragma unroll
        for (int k = 0; k < H1; ++k) sum2 += wrow[k] * o1[k];
        const float o2v = fminf(fmaxf(sum2 + l2_b[t], 0.f), 1.f);
        float part = o2v * l3_w[t];
        part += __shfl_xor(part, 1);
        part += __shfl_xor(part, 2);
        part += __shfl_xor(part, 4);
        part += __shfl_xor(part, 8);
        part += __shfl_xor(part, 16);
        if (t == 0) {
            const float o3 = (part + l3_b[0]) * OUT_SCALE;
            out[row] = 1.f / (1.f + __expf(-o3 / WDL_SCALE));
        }
    }
}

extern "C" void kernel_launch(void* const* d_in, const int* in_sizes, int n_in,
                              void* d_out, int out_size, void* d_ws, size_t ws_size,
                              hipStream_t stream) {
    const float* wf   = (const float*)d_in[0];
    const float* bf   = (const float*)d_in[1];
    const int*   side = (const int*)d_in[2];     // bool -> int32 per harness convention
    const float* ft_w = (const float*)d_in[3];
    const float* ft_b = (const float*)d_in[4];
    const float* l1_w = (const float*)d_in[5];
    const float* l1_b = (const float*)d_in[6];
    const float* l2_w = (const float*)d_in[7];
    const float* l2_b = (const float*)d_in[8];
    const float* l3_w = (const float*)d_in[9];
    const float* l3_b = (const float*)d_in[10];
    float*       out  = (float*)d_out;

    const size_t needT = (size_t)NI * H0 * sizeof(float);   // 12.6 MB
    const int tflag = (ws_size >= needT) ? 1 : 0;
    const float* ft = ft_w;
    if (tflag) {
        float* ftT = (float*)d_ws;
        nnue_ft_transpose<<<dim3(NI / 64, H0 / 64), dim3(64, 4), 0, stream>>>(ft_w, ftT);
        ft = ftT;
    }
    nnue_fwd<<<NB, 256, 0, stream>>>(wf, bf, side, ft, ft_b,
                                     l1_w, l1_b, l2_w, l2_b, l3_w, l3_b,
                                     out, tflag);
}

// Round 5
// 177.327 us; speedup vs baseline: 1.1487x; 1.0344x over previous
//
#include <hip/hip_runtime.h>
#include <math.h>

#define NB 8192
#define NI 12288
#define H0 256
#define H1 32
#define H2 32
#define MAXA 256
#define OUT_SCALE 300.0f
#define WDL_SCALE 200.0f

typedef float f32x4 __attribute__((ext_vector_type(4)));

// ---------------------------------------------------------------------------
// Kernel 1: tiled transpose ft_w [H0][NI] -> ftT [NI][H0]
// ---------------------------------------------------------------------------
__global__ __launch_bounds__(256) void nnue_ft_transpose(
    const float* __restrict__ src, float* __restrict__ dst)
{
    __shared__ float tile[64][65];
    const int bx = blockIdx.x;               // NI/64 tiles
    const int by = blockIdx.y;               // H0/64 tiles
    const int tx = threadIdx.x;              // 64
    const int ty = threadIdx.y;              // 4
    const int col = bx * 64 + tx;
    for (int j = ty; j < 64; j += 4)
        tile[j][tx] = src[(size_t)(by * 64 + j) * NI + col];
    __syncthreads();
    const int h = by * 64 + tx;
    for (int j = ty; j < 64; j += 4)
        dst[(size_t)(bx * 64 + j) * H0 + h] = tile[tx][j];
}

// ---------------------------------------------------------------------------
// Kernel 2: one 256-thread block per batch row.
//   register-prefetched nontemporal scan -> index lists ->
//   wave-parallel gather (wave w takes features w, w+4, ...; lane l owns
//   units 4l..4l+3 => each load is one coalesced 1KB ftT row per wave)
//   -> LDS combine -> side-swapped concat -> 512->32->32->1 MLP -> sigmoid
// ---------------------------------------------------------------------------
__global__ __launch_bounds__(256) void nnue_fwd(
    const float* __restrict__ wf, const float* __restrict__ bf,
    const int* __restrict__ side,
    const float* __restrict__ ft,        // ftT [NI][H0] if tflag, else ft_w [H0][NI]
    const float* __restrict__ ft_b,
    const float* __restrict__ l1_w, const float* __restrict__ l1_b,
    const float* __restrict__ l2_w, const float* __restrict__ l2_b,
    const float* __restrict__ l3_w, const float* __restrict__ l3_b,
    float* __restrict__ out, int tflag)
{
    __shared__ int   idxW[MAXA], idxB[MAXA];
    __shared__ int   cnts[2];
    __shared__ float pacc[4][2][H0] __attribute__((aligned(16)));  // wave x {W,B} x unit
    __shared__ float o0[2 * H0];
    __shared__ float o1[H1];

    const int row = blockIdx.x;
    const int t   = threadIdx.x;
    if (t < 2) cnts[t] = 0;
    __syncthreads();

    const f32x4* wf4 = (const f32x4*)(wf + (size_t)row * NI);
    const f32x4* bf4 = (const f32x4*)(bf + (size_t)row * NI);
    const float ftb = ft_b[t];

    // ---- white: prefetch 12 float4 into regs, then scan from registers ----
    {
        f32x4 v[12];
        #pragma unroll
        for (int k = 0; k < 12; ++k)
            v[k] = __builtin_nontemporal_load(&wf4[t + k * 256]);
        #pragma unroll
        for (int k = 0; k < 12; ++k) {
            const int base = (t + k * 256) * 4;
            int m = (v[k].x != 0.f ? 1 : 0) | (v[k].y != 0.f ? 2 : 0)
                  | (v[k].z != 0.f ? 4 : 0) | (v[k].w != 0.f ? 8 : 0);
            while (m) {
                const int b = __ffs(m) - 1;
                m &= m - 1;
                idxW[atomicAdd(&cnts[0], 1)] = base + b;
            }
        }
    }
    // ---- black: same ----
    {
        f32x4 v[12];
        #pragma unroll
        for (int k = 0; k < 12; ++k)
            v[k] = __builtin_nontemporal_load(&bf4[t + k * 256]);
        #pragma unroll
        for (int k = 0; k < 12; ++k) {
            const int base = (t + k * 256) * 4;
            int m = (v[k].x != 0.f ? 1 : 0) | (v[k].y != 0.f ? 2 : 0)
                  | (v[k].z != 0.f ? 4 : 0) | (v[k].w != 0.f ? 8 : 0);
            while (m) {
                const int b = __ffs(m) - 1;
                m &= m - 1;
                idxB[atomicAdd(&cnts[1], 1)] = base + b;
            }
        }
    }
    __syncthreads();

    const int nW = cnts[0], nB = cnts[1];
    const int w = t >> 6;                    // wave id 0..3
    const int l = t & 63;                    // lane

    if (tflag) {
        // ---- wave-parallel gather: ~7 independent 1KB-row loads per wave ----
        f32x4 aw0 = {0.f, 0.f, 0.f, 0.f}, aw1 = {0.f, 0.f, 0.f, 0.f};
        int i = w;
        for (; i + 4 < nW; i += 8) {
            const f32x4 r0 = *(const f32x4*)(ft + (size_t)idxW[i] * H0 + 4 * l);
            const f32x4 r1 = *(const f32x4*)(ft + (size_t)idxW[i + 4] * H0 + 4 * l);
            aw0 += r0; aw1 += r1;
        }
        if (i < nW)
            aw0 += *(const f32x4*)(ft + (size_t)idxW[i] * H0 + 4 * l);

        f32x4 ab0 = {0.f, 0.f, 0.f, 0.f}, ab1 = {0.f, 0.f, 0.f, 0.f};
        i = w;
        for (; i + 4 < nB; i += 8) {
            const f32x4 r0 = *(const f32x4*)(ft + (size_t)idxB[i] * H0 + 4 * l);
            const f32x4 r1 = *(const f32x4*)(ft + (size_t)idxB[i + 4] * H0 + 4 * l);
            ab0 += r0; ab1 += r1;
        }
        if (i < nB)
            ab0 += *(const f32x4*)(ft + (size_t)idxB[i] * H0 + 4 * l);

        *(f32x4*)&pacc[w][0][4 * l] = aw0 + aw1;
        *(f32x4*)&pacc[w][1][4 * l] = ab0 + ab1;
    } else {
        // fallback: strided reads from original layout (thread t owns unit t)
        float aW = 0.f, aB = 0.f;
        const float* ftr = ft + (size_t)t * NI;
        for (int j = 0; j < nW; ++j) aW += ftr[idxW[j]];
        for (int j = 0; j < nB; ++j) aB += ftr[idxB[j]];
        if (w == 0) { pacc[0][0][t % 64] = 0.f; }  // unused path marker
        // store full result directly (serial layout): emulate combine below
        pacc[0][0][t] = aW; pacc[1][0][t] = 0.f; pacc[2][0][t] = 0.f; pacc[3][0][t] = 0.f;
        pacc[0][1][t] = aB; pacc[1][1][t] = 0.f; pacc[2][1][t] = 0.f; pacc[3][1][t] = 0.f;
    }
    __syncthreads();

    // ---- combine wave partials; side-swapped concat (thread t owns unit t) ----
    const float accW = ftb + ((pacc[0][0][t] + pacc[1][0][t]) + (pacc[2][0][t] + pacc[3][0][t]));
    const float accB = ftb + ((pacc[0][1][t] + pacc[1][1][t]) + (pacc[2][1][t] + pacc[3][1][t]));
    const bool s = side[row] != 0;
    const float wv = fminf(fmaxf(accW, 0.f), 1.f);
    const float bv = fminf(fmaxf(accB, 0.f), 1.f);
    o0[t]      = s ? wv : bv;
    o0[t + H0] = s ? bv : wv;
    __syncthreads();

    // ---- l1: 32 outputs x 512 inputs, 8 threads per output ----
    {
        const int j = t >> 3, p = t & 7;
        const float* wrow = l1_w + j * (2 * H0);
        float sum = 0.f;
        #pragma unroll
        for (int m = 0; m < 64; ++m) {
            const int k = p + 8 * m;         // stride-8: conflict-free LDS
            sum += wrow[k] * o0[k];
        }
        sum += __shfl_xor(sum, 1);
        sum += __shfl_xor(sum, 2);
        sum += __shfl_xor(sum, 4);
        if (p == 0) o1[j] = fminf(fmaxf(sum + l1_b[j], 0.f), 1.f);
    }
    __syncthreads();

    // ---- l2 (32x32) + l3 (1x32) + sigmoid ----
    if (t < 32) {
        const float* wrow = l2_w + t * H1;
        float sum2 = 0.f;
        #pragma unroll
        for (int k = 0; k < H1; ++k) sum2 += wrow[k] * o1[k];
        const float o2v = fminf(fmaxf(sum2 + l2_b[t], 0.f), 1.f);
        float part = o2v * l3_w[t];
        part += __shfl_xor(part, 1);
        part += __shfl_xor(part, 2);
        part += __shfl_xor(part, 4);
        part += __shfl_xor(part, 8);
        part += __shfl_xor(part, 16);
        if (t == 0) {
            const float o3 = (part + l3_b[0]) * OUT_SCALE;
            out[row] = 1.f / (1.f + __expf(-o3 / WDL_SCALE));
        }
    }
}

extern "C" void kernel_launch(void* const* d_in, const int* in_sizes, int n_in,
                              void* d_out, int out_size, void* d_ws, size_t ws_size,
                              hipStream_t stream) {
    const float* wf   = (const float*)d_in[0];
    const float* bf   = (const float*)d_in[1];
    const int*   side = (const int*)d_in[2];     // bool -> int32 per harness convention
    const float* ft_w = (const float*)d_in[3];
    const float* ft_b = (const float*)d_in[4];
    const float* l1_w = (const float*)d_in[5];
    const float* l1_b = (const float*)d_in[6];
    const float* l2_w = (const float*)d_in[7];
    const float* l2_b = (const float*)d_in[8];
    const float* l3_w = (const float*)d_in[9];
    const float* l3_b = (const float*)d_in[10];
    float*       out  = (float*)d_out;

    const size_t needT = (size_t)NI * H0 * sizeof(float);   // 12.6 MB
    const int tflag = (ws_size >= needT) ? 1 : 0;
    const float* ft = ft_w;
    if (tflag) {
        float* ftT = (float*)d_ws;
        nnue_ft_transpose<<<dim3(NI / 64, H0 / 64), dim3(64, 4), 0, stream>>>(ft_w, ftT);
        ft = ftT;
    }
    nnue_fwd<<<NB, 256, 0, stream>>>(wf, bf, side, ft, ft_b,
                                     l1_w, l1_b, l2_w, l2_b, l3_w, l3_b,
                                     out, tflag);
}